// Round 9
// baseline (2174.668 us; speedup 1.0000x reference)
//
#include <hip/hip_runtime.h>
#include <cstdint>
#include <cstddef>

#define B_ 64
#define T_ 512
#define I_ 256
#define H_ 1024
#define O_ 128

// Phase-B geometry: 8 groups (8 batch rows) x 8 slices (128 H-cols), 512-thr
// WGs; group = blockIdx.x & 7 (XCD-pure under %8 round-robin, verified at
// runtime). THIS ROUND: exchange ops FORCED to validated sc0 sc1 semantics;
// handshake result only signals XCD-purity via a deliberate ~0.4ms delay.
#define NGRP  8
#define NSLC  8
#define GROWS 8
#define SCOLS 128

typedef __attribute__((ext_vector_type(8))) short short8;   // 8 x bf16 frag
typedef __attribute__((ext_vector_type(4))) float f32x4;    // MFMA accumulator

__device__ __forceinline__ unsigned short f2bf(float f) {
    union { float f; unsigned int u; } v; v.f = f;
    unsigned int r = v.u + 0x7fffu + ((v.u >> 16) & 1u);   // RNE
    return (unsigned short)(r >> 16);
}
__device__ __forceinline__ float bf2f(unsigned short h) {
    union { float f; unsigned int u; } v; v.u = ((unsigned int)h) << 16;
    return v.f;
}
__device__ __forceinline__ short8 pack8(const float* p) {
    float4 a = *(const float4*)p;
    float4 b = *(const float4*)(p + 4);
    short8 r;
    r[0] = (short)f2bf(a.x); r[1] = (short)f2bf(a.y);
    r[2] = (short)f2bf(a.z); r[3] = (short)f2bf(a.w);
    r[4] = (short)f2bf(b.x); r[5] = (short)f2bf(b.y);
    r[6] = (short)f2bf(b.z); r[7] = (short)f2bf(b.w);
    return r;
}
__device__ __forceinline__ f32x4 zero4() {
    f32x4 v; v[0] = 0.f; v[1] = 0.f; v[2] = 0.f; v[3] = 0.f; return v;
}
__device__ __forceinline__ void vdrain() {
    asm volatile("s_waitcnt vmcnt(0)" ::: "memory");
}

// ---------------------------------------------------------------------------
// Phase A: xp[t][b][h] = x[b][t][:] . W_ih[h][:] + b_ih[h] + b_hh[h]
// (unchanged; validated)
// ---------------------------------------------------------------------------
#define XS 264   // LDS row stride (shorts)

__global__ __launch_bounds__(256) void xproj_kernel(
        const float* __restrict__ x, const float* __restrict__ W_ih,
        const float* __restrict__ b_ih, const float* __restrict__ b_hh,
        unsigned short* __restrict__ xp) {
    const int ntile = blockIdx.x;        // 0..15
    const int tg    = blockIdx.y;        // 0..63 (8 t's each)
    const int tid   = threadIdx.x;
    const int wave  = tid >> 6, lane = tid & 63;
    const int m     = lane & 15, quad = lane >> 4;
    const int wrow  = (wave & 1) * 32;
    const int wcol  = (wave >> 1) * 32;

    __shared__ unsigned short lds_x[64 * XS];

    short8 bfr[2][8];
    float  bias[2];
    #pragma unroll
    for (int ct = 0; ct < 2; ++ct) {
        const int col = ntile * 64 + wcol + ct * 16 + m;
        bias[ct] = b_ih[col] + b_hh[col];
        #pragma unroll
        for (int ks = 0; ks < 8; ++ks)
            bfr[ct][ks] = pack8(W_ih + (size_t)col * I_ + ks * 32 + quad * 8);
    }

    for (int it = 0; it < 8; ++it) {
        const int t = tg * 8 + it;
        #pragma unroll
        for (int j = 0; j < 16; ++j) {
            const int row = j * 4 + wave;
            float4 v = *(const float4*)(x + ((size_t)row * T_ + t) * I_ + lane * 4);
            uint2 p;
            p.x = (unsigned)f2bf(v.x) | ((unsigned)f2bf(v.y) << 16);
            p.y = (unsigned)f2bf(v.z) | ((unsigned)f2bf(v.w) << 16);
            *(uint2*)(&lds_x[row * XS + lane * 4]) = p;
        }
        __syncthreads();

        f32x4 acc[2][2];
        #pragma unroll
        for (int i = 0; i < 2; ++i)
            #pragma unroll
            for (int j = 0; j < 2; ++j) acc[i][j] = zero4();

        #pragma unroll
        for (int ks = 0; ks < 8; ++ks) {
            const int kb = ks * 32 + quad * 8;
            short8 af[2];
            #pragma unroll
            for (int rt = 0; rt < 2; ++rt)
                af[rt] = *(const short8*)(&lds_x[(wrow + rt * 16 + m) * XS + kb]);
            #pragma unroll
            for (int rt = 0; rt < 2; ++rt)
                #pragma unroll
                for (int ct = 0; ct < 2; ++ct)
                    acc[rt][ct] = __builtin_amdgcn_mfma_f32_16x16x32_bf16(
                        af[rt], bfr[ct][ks], acc[rt][ct], 0, 0, 0);
        }

        #pragma unroll
        for (int ct = 0; ct < 2; ++ct) {
            const int col = ntile * 64 + wcol + ct * 16 + m;
            #pragma unroll
            for (int rt = 0; rt < 2; ++rt)
                #pragma unroll
                for (int r = 0; r < 4; ++r) {
                    const int bl = wrow + rt * 16 + quad * 4 + r;
                    xp[((size_t)t * B_ + bl) * H_ + col] =
                        f2bf(acc[rt][ct][r] + bias[ct]);
                }
        }
        __syncthreads();
    }
}

// ---------------------------------------------------------------------------
// Phase B: persistent recurrence, validated per-wave-flag dataflow protocol
// (sc0 sc1 system-scope everywhere — byte-identical op semantics to the
// 2014us-validated kernel), in the new 8x8 geometry. Handshake detects
// XCD-purity of groups and signals it via timing only.
// ---------------------------------------------------------------------------
#define LDS_STRIDE 1032   // row stride (shorts); rows 16B-aligned
#define PO_S 20           // per-wave out tile stride (shorts)
#define POLL_BOUND 4096

__global__ __launch_bounds__(512, 1) void rnn_kernel(
        const float* __restrict__ W_hh, const unsigned short* __restrict__ xp,
        unsigned short* __restrict__ hbuf, unsigned int* __restrict__ flags,
        unsigned int* __restrict__ xcdbuf) {
    const int slice = blockIdx.x >> 3;   // 0..7 (128 H-cols each)
    const int group = blockIdx.x & 7;    // 0..7 (8 batch rows each)
    const int tid   = threadIdx.x;
    const int wave  = tid >> 6, lane = tid & 63;
    const int m     = lane & 15, quad = lane >> 4;
    const int col   = slice * SCOLS + wave * 16 + m;   // this lane's B column

    __shared__ unsigned short lds_h[GROWS * LDS_STRIDE];
    __shared__ unsigned short lds_po[8][GROWS * PO_S];

    // Preload W_hh B-frags: bfrag[ks] = W_hh[col][ks*32 + quad*8 ..]
    short8 bfrag[32];
    #pragma unroll
    for (int ks = 0; ks < 32; ++ks)
        bfrag[ks] = pack8(W_hh + (size_t)col * H_ + ks * 32 + quad * 8);

    unsigned int* gflags = flags + group * 64;      // 64 wave-flags per group
    unsigned int* myflag = gflags + slice * 8 + wave;
    const unsigned int* pollp = gflags + lane;
    unsigned short* lds_po_w = &lds_po[wave][0];

    // ---- XCD co-residency handshake: DIAGNOSTIC ONLY this round ----
    unsigned xcc = 0xffu;
    asm volatile("s_getreg_b32 %0, hwreg(HW_REG_XCC_ID)" : "=s"(xcc));
    if (tid == 0) {
        unsigned v = 0x100u | (xcc & 0xffu);
        asm volatile("global_store_dword %0, %1, off sc0 sc1"
                     :: "v"(xcdbuf + blockIdx.x), "v"(v) : "memory");
        vdrain();
    }
    bool fast = false;
    {
        const unsigned int* q = xcdbuf + group + 8 * (lane & 7);
        int spins = 0;
        for (;;) {
            unsigned v;
            asm volatile("global_load_dword %0, %1, off sc0 sc1\n\t"
                         "s_waitcnt vmcnt(0)"
                         : "=v"(v) : "v"(q) : "memory");
            if (__all((v & 0x100u) != 0u)) {
                unsigned ref = __shfl(v, 0, 64);
                fast = __all(v == ref) && ((ref & 0xffu) < 8u);
                break;
            }
            if (++spins > (1 << 16)) { fast = false; break; }
        }
    }
    // timing channel: if group 0 is XCD-pure, stall the dataflow ~0.4ms.
    // (pass @ ~2.4ms => pure; pass @ ~2.0ms => not pure; fail => geometry bug)
    if (blockIdx.x == 0 && tid == 0 && fast) {
        for (int i = 0; i < 120; ++i) __builtin_amdgcn_s_sleep(127);
    }

    const int srow = tid >> 6, useg = tid & 63;       // staging role (8x64)
    const int prow = lane >> 3, pseg = lane & 7;      // publish role (8x8)

    for (int t = 0; t < T_; ++t) {
        const unsigned short* hsrc = hbuf + (size_t)(t & 1) * (B_ * H_)
                                          + (size_t)group * GROWS * H_;
        unsigned short* hdst = hbuf + (size_t)((t + 1) & 1) * (B_ * H_);

        // xp prefetch (plain cached loads). quads 2,3 duplicate 0,1 (unused).
        unsigned short xpv[4];
        {
            const unsigned short* xpp =
                xp + ((size_t)t * B_ + group * GROWS + (quad & 1) * 4) * H_ + col;
            #pragma unroll
            for (int r = 0; r < 4; ++r) xpv[r] = xpp[(size_t)r * H_];
        }

        // poll: all 64 producer-wave flags of this group >= t (bounded)
        if (t > 0) {
            const unsigned target = (unsigned)t;
            int spins = 0;
            while (true) {
                unsigned fv;
                asm volatile(
                    "global_load_dword %0, %1, off sc0 sc1\n\t"
                    "s_waitcnt vmcnt(0)"
                    : "=v"(fv) : "v"(pollp) : "memory");
                if (__ballot(fv >= target) == ~0ull) break;
                if (++spins >= POLL_BOUND) break;   // stall -> absmax, not hang
            }
        }

        // cooperative stage: 8 rows x 1024 bf16 (16 KB) -> LDS
        {
            const unsigned short* rp = hsrc + (size_t)srow * H_;
            uint4 sv0, sv1;
            asm volatile("global_load_dwordx4 %0, %1, off sc0 sc1"
                         : "=v"(sv0) : "v"(rp + useg * 8) : "memory");
            asm volatile("global_load_dwordx4 %0, %1, off sc0 sc1"
                         : "=v"(sv1) : "v"(rp + (useg + 64) * 8) : "memory");
            vdrain();
            *(uint4*)(&lds_h[srow * LDS_STRIDE + useg * 8]) = sv0;
            *(uint4*)(&lds_h[srow * LDS_STRIDE + (useg + 64) * 8]) = sv1;
        }
        __syncthreads();   // S_b: staged data visible to all waves

        // K loop: A rows 8..15 duplicate 0..7 via (m&7); C rows 8..15 unused.
        f32x4 acc[4];
        #pragma unroll
        for (int j = 0; j < 4; ++j) acc[j] = zero4();
        #pragma unroll
        for (int ks = 0; ks < 32; ks += 4) {
            #pragma unroll
            for (int j = 0; j < 4; ++j) {
                short8 a = *(const short8*)(
                    &lds_h[(m & 7) * LDS_STRIDE + (ks + j) * 32 + quad * 8]);
                acc[j] = __builtin_amdgcn_mfma_f32_16x16x32_bf16(
                    a, bfrag[ks + j], acc[j], 0, 0, 0);
            }
        }

        // epilogue: +xp, tanh -> per-wave LDS transpose tile (8 rows x 16 cols)
        if (quad < 2) {
            #pragma unroll
            for (int r = 0; r < 4; ++r) {
                float v = acc[0][r] + acc[1][r] + acc[2][r] + acc[3][r]
                        + bf2f(xpv[r]);
                v = tanhf(v);
                lds_po_w[(quad * 4 + r) * PO_S + m] = f2bf(v);
            }
        }
        // wave-local readback (compiler inserts lgkmcnt) + coherent publish
        {
            unsigned v = *(const unsigned*)(&lds_po_w[prow * PO_S + pseg * 2]);
            const void* p = hdst + (size_t)(group * GROWS + prow) * H_
                            + slice * SCOLS + wave * 16 + pseg * 2;
            asm volatile("global_store_dword %0, %1, off sc0 sc1"
                         :: "v"(p), "v"(v) : "memory");
            vdrain();
        }
        // publish flag (own chunk fully visible at the coherence point)
        if (lane == 0 && t < T_ - 1) {
            unsigned fv = (unsigned)(t + 1);
            asm volatile("global_store_dword %0, %1, off sc0 sc1"
                         :: "v"(myflag), "v"(fv) : "memory");
        }
        __syncthreads();   // S_a: all waves done reading lds_h before restage
    }
}

// ---------------------------------------------------------------------------
// Phase C: out[b][o] = h_final[b][:] . W_lin[o][:] + b_lin[o]; one wave/output
// ---------------------------------------------------------------------------
__global__ __launch_bounds__(256) void out_kernel(
        const unsigned short* __restrict__ hfinal, const float* __restrict__ W_lin,
        const float* __restrict__ b_lin, float* __restrict__ out) {
    const int gwave = (int)((blockIdx.x * 256 + threadIdx.x) >> 6);  // 0..8191
    const int lane  = threadIdx.x & 63;
    const int b = gwave >> 7, o = gwave & 127;

    const unsigned short* hp = hfinal + (size_t)b * H_ + lane * 16;
    const float*          wp = W_lin  + (size_t)o * H_ + lane * 16;
    float s = 0.f;
    #pragma unroll
    for (int j = 0; j < 16; ++j) s += bf2f(hp[j]) * wp[j];
    #pragma unroll
    for (int d = 32; d > 0; d >>= 1) s += __shfl_down(s, d, 64);
    if (lane == 0) out[(size_t)b * O_ + o] = s + b_lin[o];
}

// ---------------------------------------------------------------------------
extern "C" void kernel_launch(void* const* d_in, const int* in_sizes, int n_in,
                              void* d_out, int out_size, void* d_ws, size_t ws_size,
                              hipStream_t stream) {
    const float* x     = (const float*)d_in[0];
    const float* W_ih  = (const float*)d_in[1];
    const float* W_hh  = (const float*)d_in[2];
    const float* b_ih  = (const float*)d_in[3];
    const float* b_hh  = (const float*)d_in[4];
    const float* W_lin = (const float*)d_in[5];
    const float* b_lin = (const float*)d_in[6];

    const size_t XP_ELEMS = (size_t)T_ * B_ * H_;        // 33.5M bf16 = 64 MB
    unsigned short* xp     = (unsigned short*)d_ws;
    unsigned short* hbuf   = xp + XP_ELEMS;              // 2 x (64*1024) bf16
    unsigned int*   flags  = (unsigned int*)(hbuf + 2 * (size_t)B_ * H_);
    unsigned int*   xcdbuf = flags + NGRP * 64;

    // zero h ping-pong + flags + xcd handshake area
    (void)hipMemsetAsync(hbuf, 0,
                         2 * (size_t)B_ * H_ * sizeof(unsigned short)
                         + (NGRP * 64 + 64) * sizeof(unsigned int), stream);

    dim3 gA(H_ / 64, T_ / 8);   // (ntile, tgroup)
    xproj_kernel<<<gA, 256, 0, stream>>>(x, W_ih, b_ih, b_hh, xp);
    rnn_kernel<<<64, 512, 0, stream>>>(W_hh, xp, hbuf, flags, xcdbuf);
    out_kernel<<<(B_ * O_) / 4, 256, 0, stream>>>(hbuf, W_lin, b_lin, (float*)d_out);
}

// Round 10
// 1802.876 us; speedup vs baseline: 1.2062x; 1.2062x over previous
//
#include <hip/hip_runtime.h>
#include <cstdint>
#include <cstddef>

#define B_ 64
#define T_ 512
#define I_ 256
#define H_ 1024
#define O_ 128

// Phase-B geometry (validated round 9): 8 groups (8 batch rows) x 8 slices
// (128 H-cols), 512-thread WGs. Exchange: validated sc0 sc1 protocol.
// This round: r9 minus diagnostic sleep/handshake -> true 8x8 steady state.
#define NGRP  8
#define NSLC  8
#define GROWS 8
#define SCOLS 128

typedef __attribute__((ext_vector_type(8))) short short8;   // 8 x bf16 frag
typedef __attribute__((ext_vector_type(4))) float f32x4;    // MFMA accumulator

__device__ __forceinline__ unsigned short f2bf(float f) {
    union { float f; unsigned int u; } v; v.f = f;
    unsigned int r = v.u + 0x7fffu + ((v.u >> 16) & 1u);   // RNE
    return (unsigned short)(r >> 16);
}
__device__ __forceinline__ float bf2f(unsigned short h) {
    union { float f; unsigned int u; } v; v.u = ((unsigned int)h) << 16;
    return v.f;
}
__device__ __forceinline__ short8 pack8(const float* p) {
    float4 a = *(const float4*)p;
    float4 b = *(const float4*)(p + 4);
    short8 r;
    r[0] = (short)f2bf(a.x); r[1] = (short)f2bf(a.y);
    r[2] = (short)f2bf(a.z); r[3] = (short)f2bf(a.w);
    r[4] = (short)f2bf(b.x); r[5] = (short)f2bf(b.y);
    r[6] = (short)f2bf(b.z); r[7] = (short)f2bf(b.w);
    return r;
}
__device__ __forceinline__ f32x4 zero4() {
    f32x4 v; v[0] = 0.f; v[1] = 0.f; v[2] = 0.f; v[3] = 0.f; return v;
}
__device__ __forceinline__ void vdrain() {
    asm volatile("s_waitcnt vmcnt(0)" ::: "memory");
}

// ---------------------------------------------------------------------------
// Phase A: xp[t][b][h] = x[b][t][:] . W_ih[h][:] + b_ih[h] + b_hh[h]
// (unchanged; validated)
// ---------------------------------------------------------------------------
#define XS 264   // LDS row stride (shorts)

__global__ __launch_bounds__(256) void xproj_kernel(
        const float* __restrict__ x, const float* __restrict__ W_ih,
        const float* __restrict__ b_ih, const float* __restrict__ b_hh,
        unsigned short* __restrict__ xp) {
    const int ntile = blockIdx.x;        // 0..15
    const int tg    = blockIdx.y;        // 0..63 (8 t's each)
    const int tid   = threadIdx.x;
    const int wave  = tid >> 6, lane = tid & 63;
    const int m     = lane & 15, quad = lane >> 4;
    const int wrow  = (wave & 1) * 32;
    const int wcol  = (wave >> 1) * 32;

    __shared__ unsigned short lds_x[64 * XS];

    short8 bfr[2][8];
    float  bias[2];
    #pragma unroll
    for (int ct = 0; ct < 2; ++ct) {
        const int col = ntile * 64 + wcol + ct * 16 + m;
        bias[ct] = b_ih[col] + b_hh[col];
        #pragma unroll
        for (int ks = 0; ks < 8; ++ks)
            bfr[ct][ks] = pack8(W_ih + (size_t)col * I_ + ks * 32 + quad * 8);
    }

    for (int it = 0; it < 8; ++it) {
        const int t = tg * 8 + it;
        #pragma unroll
        for (int j = 0; j < 16; ++j) {
            const int row = j * 4 + wave;
            float4 v = *(const float4*)(x + ((size_t)row * T_ + t) * I_ + lane * 4);
            uint2 p;
            p.x = (unsigned)f2bf(v.x) | ((unsigned)f2bf(v.y) << 16);
            p.y = (unsigned)f2bf(v.z) | ((unsigned)f2bf(v.w) << 16);
            *(uint2*)(&lds_x[row * XS + lane * 4]) = p;
        }
        __syncthreads();

        f32x4 acc[2][2];
        #pragma unroll
        for (int i = 0; i < 2; ++i)
            #pragma unroll
            for (int j = 0; j < 2; ++j) acc[i][j] = zero4();

        #pragma unroll
        for (int ks = 0; ks < 8; ++ks) {
            const int kb = ks * 32 + quad * 8;
            short8 af[2];
            #pragma unroll
            for (int rt = 0; rt < 2; ++rt)
                af[rt] = *(const short8*)(&lds_x[(wrow + rt * 16 + m) * XS + kb]);
            #pragma unroll
            for (int rt = 0; rt < 2; ++rt)
                #pragma unroll
                for (int ct = 0; ct < 2; ++ct)
                    acc[rt][ct] = __builtin_amdgcn_mfma_f32_16x16x32_bf16(
                        af[rt], bfr[ct][ks], acc[rt][ct], 0, 0, 0);
        }

        #pragma unroll
        for (int ct = 0; ct < 2; ++ct) {
            const int col = ntile * 64 + wcol + ct * 16 + m;
            #pragma unroll
            for (int rt = 0; rt < 2; ++rt)
                #pragma unroll
                for (int r = 0; r < 4; ++r) {
                    const int bl = wrow + rt * 16 + quad * 4 + r;
                    xp[((size_t)t * B_ + bl) * H_ + col] =
                        f2bf(acc[rt][ct][r] + bias[ct]);
                }
        }
        __syncthreads();
    }
}

// ---------------------------------------------------------------------------
// Phase B: persistent recurrence, validated per-wave-flag dataflow protocol
// (sc0 sc1 system-scope — validated semantics), 8x8 geometry (validated r9).
// ---------------------------------------------------------------------------
#define LDS_STRIDE 1032   // row stride (shorts); rows 16B-aligned
#define PO_S 20           // per-wave out tile stride (shorts)
#define POLL_BOUND 4096

__global__ __launch_bounds__(512, 1) void rnn_kernel(
        const float* __restrict__ W_hh, const unsigned short* __restrict__ xp,
        unsigned short* __restrict__ hbuf, unsigned int* __restrict__ flags) {
    const int slice = blockIdx.x >> 3;   // 0..7 (128 H-cols each)
    const int group = blockIdx.x & 7;    // 0..7 (8 batch rows each)
    const int tid   = threadIdx.x;
    const int wave  = tid >> 6, lane = tid & 63;
    const int m     = lane & 15, quad = lane >> 4;
    const int col   = slice * SCOLS + wave * 16 + m;   // this lane's B column

    __shared__ unsigned short lds_h[GROWS * LDS_STRIDE];
    __shared__ unsigned short lds_po[8][GROWS * PO_S];

    // Preload W_hh B-frags: bfrag[ks] = W_hh[col][ks*32 + quad*8 ..]
    short8 bfrag[32];
    #pragma unroll
    for (int ks = 0; ks < 32; ++ks)
        bfrag[ks] = pack8(W_hh + (size_t)col * H_ + ks * 32 + quad * 8);

    unsigned int* gflags = flags + group * 64;      // 64 wave-flags per group
    unsigned int* myflag = gflags + slice * 8 + wave;
    const unsigned int* pollp = gflags + lane;
    unsigned short* lds_po_w = &lds_po[wave][0];

    const int srow = tid >> 6, useg = tid & 63;       // staging role (8x64)
    const int prow = lane >> 3, pseg = lane & 7;      // publish role (8x8)

    for (int t = 0; t < T_; ++t) {
        const unsigned short* hsrc = hbuf + (size_t)(t & 1) * (B_ * H_)
                                          + (size_t)group * GROWS * H_;
        unsigned short* hdst = hbuf + (size_t)((t + 1) & 1) * (B_ * H_);

        // xp prefetch (plain cached loads). quads 2,3 duplicate 0,1 (unused).
        unsigned short xpv[4];
        {
            const unsigned short* xpp =
                xp + ((size_t)t * B_ + group * GROWS + (quad & 1) * 4) * H_ + col;
            #pragma unroll
            for (int r = 0; r < 4; ++r) xpv[r] = xpp[(size_t)r * H_];
        }

        // poll: all 64 producer-wave flags of this group >= t (bounded)
        if (t > 0) {
            const unsigned target = (unsigned)t;
            int spins = 0;
            while (true) {
                unsigned fv;
                asm volatile(
                    "global_load_dword %0, %1, off sc0 sc1\n\t"
                    "s_waitcnt vmcnt(0)"
                    : "=v"(fv) : "v"(pollp) : "memory");
                if (__ballot(fv >= target) == ~0ull) break;
                if (++spins >= POLL_BOUND) break;   // stall -> absmax, not hang
            }
        }

        // cooperative stage: 8 rows x 1024 bf16 (16 KB) -> LDS
        {
            const unsigned short* rp = hsrc + (size_t)srow * H_;
            uint4 sv0, sv1;
            asm volatile("global_load_dwordx4 %0, %1, off sc0 sc1"
                         : "=v"(sv0) : "v"(rp + useg * 8) : "memory");
            asm volatile("global_load_dwordx4 %0, %1, off sc0 sc1"
                         : "=v"(sv1) : "v"(rp + (useg + 64) * 8) : "memory");
            vdrain();
            *(uint4*)(&lds_h[srow * LDS_STRIDE + useg * 8]) = sv0;
            *(uint4*)(&lds_h[srow * LDS_STRIDE + (useg + 64) * 8]) = sv1;
        }
        __syncthreads();   // S_b: staged data visible to all waves

        // K loop: A rows 8..15 duplicate 0..7 via (m&7); C rows 8..15 unused.
        f32x4 acc[4];
        #pragma unroll
        for (int j = 0; j < 4; ++j) acc[j] = zero4();
        #pragma unroll
        for (int ks = 0; ks < 32; ks += 4) {
            #pragma unroll
            for (int j = 0; j < 4; ++j) {
                short8 a = *(const short8*)(
                    &lds_h[(m & 7) * LDS_STRIDE + (ks + j) * 32 + quad * 8]);
                acc[j] = __builtin_amdgcn_mfma_f32_16x16x32_bf16(
                    a, bfrag[ks + j], acc[j], 0, 0, 0);
            }
        }

        // epilogue: +xp, tanh -> per-wave LDS transpose tile (8 rows x 16 cols)
        if (quad < 2) {
            #pragma unroll
            for (int r = 0; r < 4; ++r) {
                float v = acc[0][r] + acc[1][r] + acc[2][r] + acc[3][r]
                        + bf2f(xpv[r]);
                v = tanhf(v);
                lds_po_w[(quad * 4 + r) * PO_S + m] = f2bf(v);
            }
        }
        // wave-local readback (compiler inserts lgkmcnt) + coherent publish
        {
            unsigned v = *(const unsigned*)(&lds_po_w[prow * PO_S + pseg * 2]);
            const void* p = hdst + (size_t)(group * GROWS + prow) * H_
                            + slice * SCOLS + wave * 16 + pseg * 2;
            asm volatile("global_store_dword %0, %1, off sc0 sc1"
                         :: "v"(p), "v"(v) : "memory");
            vdrain();
        }
        // publish flag (own chunk fully visible at the coherence point)
        if (lane == 0 && t < T_ - 1) {
            unsigned fv = (unsigned)(t + 1);
            asm volatile("global_store_dword %0, %1, off sc0 sc1"
                         :: "v"(myflag), "v"(fv) : "memory");
        }
        __syncthreads();   // S_a: all waves done reading lds_h before restage
    }
}

// ---------------------------------------------------------------------------
// Phase C: out[b][o] = h_final[b][:] . W_lin[o][:] + b_lin[o]; one wave/output
// ---------------------------------------------------------------------------
__global__ __launch_bounds__(256) void out_kernel(
        const unsigned short* __restrict__ hfinal, const float* __restrict__ W_lin,
        const float* __restrict__ b_lin, float* __restrict__ out) {
    const int gwave = (int)((blockIdx.x * 256 + threadIdx.x) >> 6);  // 0..8191
    const int lane  = threadIdx.x & 63;
    const int b = gwave >> 7, o = gwave & 127;

    const unsigned short* hp = hfinal + (size_t)b * H_ + lane * 16;
    const float*          wp = W_lin  + (size_t)o * H_ + lane * 16;
    float s = 0.f;
    #pragma unroll
    for (int j = 0; j < 16; ++j) s += bf2f(hp[j]) * wp[j];
    #pragma unroll
    for (int d = 32; d > 0; d >>= 1) s += __shfl_down(s, d, 64);
    if (lane == 0) out[(size_t)b * O_ + o] = s + b_lin[o];
}

// ---------------------------------------------------------------------------
extern "C" void kernel_launch(void* const* d_in, const int* in_sizes, int n_in,
                              void* d_out, int out_size, void* d_ws, size_t ws_size,
                              hipStream_t stream) {
    const float* x     = (const float*)d_in[0];
    const float* W_ih  = (const float*)d_in[1];
    const float* W_hh  = (const float*)d_in[2];
    const float* b_ih  = (const float*)d_in[3];
    const float* b_hh  = (const float*)d_in[4];
    const float* W_lin = (const float*)d_in[5];
    const float* b_lin = (const float*)d_in[6];

    const size_t XP_ELEMS = (size_t)T_ * B_ * H_;        // 33.5M bf16 = 64 MB
    unsigned short* xp    = (unsigned short*)d_ws;
    unsigned short* hbuf  = xp + XP_ELEMS;               // 2 x (64*1024) bf16
    unsigned int*   flags = (unsigned int*)(hbuf + 2 * (size_t)B_ * H_);

    // zero h ping-pong + flags
    (void)hipMemsetAsync(hbuf, 0,
                         2 * (size_t)B_ * H_ * sizeof(unsigned short)
                         + NGRP * 64 * sizeof(unsigned int), stream);

    dim3 gA(H_ / 64, T_ / 8);   // (ntile, tgroup)
    xproj_kernel<<<gA, 256, 0, stream>>>(x, W_ih, b_ih, b_hh, xp);
    rnn_kernel<<<64, 512, 0, stream>>>(W_hh, xp, hbuf, flags);
    out_kernel<<<(B_ * O_) / 4, 256, 0, stream>>>(hbuf, W_lin, b_lin, (float*)d_out);
}

// Round 11
// 1784.979 us; speedup vs baseline: 1.2183x; 1.0100x over previous
//
#include <hip/hip_runtime.h>
#include <cstdint>
#include <cstddef>

#define B_ 64
#define T_ 512
#define I_ 256
#define H_ 1024
#define O_ 128

// Phase-B geometry (validated r9/r10): 8 groups (8 batch rows) x 8 slices
// (128 H-cols), 512-thread WGs, sc0 sc1 exchange protocol.
// THIS ROUND (single variable): poll storm reduction — wave0-only poll +
// per-WG flags (8/group, published after the S_a all-waves-drained barrier).
#define NGRP  8
#define NSLC  8
#define GROWS 8
#define SCOLS 128

typedef __attribute__((ext_vector_type(8))) short short8;   // 8 x bf16 frag
typedef __attribute__((ext_vector_type(4))) float f32x4;    // MFMA accumulator

__device__ __forceinline__ unsigned short f2bf(float f) {
    union { float f; unsigned int u; } v; v.f = f;
    unsigned int r = v.u + 0x7fffu + ((v.u >> 16) & 1u);   // RNE
    return (unsigned short)(r >> 16);
}
__device__ __forceinline__ float bf2f(unsigned short h) {
    union { float f; unsigned int u; } v; v.u = ((unsigned int)h) << 16;
    return v.f;
}
__device__ __forceinline__ short8 pack8(const float* p) {
    float4 a = *(const float4*)p;
    float4 b = *(const float4*)(p + 4);
    short8 r;
    r[0] = (short)f2bf(a.x); r[1] = (short)f2bf(a.y);
    r[2] = (short)f2bf(a.z); r[3] = (short)f2bf(a.w);
    r[4] = (short)f2bf(b.x); r[5] = (short)f2bf(b.y);
    r[6] = (short)f2bf(b.z); r[7] = (short)f2bf(b.w);
    return r;
}
__device__ __forceinline__ f32x4 zero4() {
    f32x4 v; v[0] = 0.f; v[1] = 0.f; v[2] = 0.f; v[3] = 0.f; return v;
}
__device__ __forceinline__ void vdrain() {
    asm volatile("s_waitcnt vmcnt(0)" ::: "memory");
}

// ---------------------------------------------------------------------------
// Phase A: xp[t][b][h] = x[b][t][:] . W_ih[h][:] + b_ih[h] + b_hh[h]
// (unchanged; validated)
// ---------------------------------------------------------------------------
#define XS 264   // LDS row stride (shorts)

__global__ __launch_bounds__(256) void xproj_kernel(
        const float* __restrict__ x, const float* __restrict__ W_ih,
        const float* __restrict__ b_ih, const float* __restrict__ b_hh,
        unsigned short* __restrict__ xp) {
    const int ntile = blockIdx.x;        // 0..15
    const int tg    = blockIdx.y;        // 0..63 (8 t's each)
    const int tid   = threadIdx.x;
    const int wave  = tid >> 6, lane = tid & 63;
    const int m     = lane & 15, quad = lane >> 4;
    const int wrow  = (wave & 1) * 32;
    const int wcol  = (wave >> 1) * 32;

    __shared__ unsigned short lds_x[64 * XS];

    short8 bfr[2][8];
    float  bias[2];
    #pragma unroll
    for (int ct = 0; ct < 2; ++ct) {
        const int col = ntile * 64 + wcol + ct * 16 + m;
        bias[ct] = b_ih[col] + b_hh[col];
        #pragma unroll
        for (int ks = 0; ks < 8; ++ks)
            bfr[ct][ks] = pack8(W_ih + (size_t)col * I_ + ks * 32 + quad * 8);
    }

    for (int it = 0; it < 8; ++it) {
        const int t = tg * 8 + it;
        #pragma unroll
        for (int j = 0; j < 16; ++j) {
            const int row = j * 4 + wave;
            float4 v = *(const float4*)(x + ((size_t)row * T_ + t) * I_ + lane * 4);
            uint2 p;
            p.x = (unsigned)f2bf(v.x) | ((unsigned)f2bf(v.y) << 16);
            p.y = (unsigned)f2bf(v.z) | ((unsigned)f2bf(v.w) << 16);
            *(uint2*)(&lds_x[row * XS + lane * 4]) = p;
        }
        __syncthreads();

        f32x4 acc[2][2];
        #pragma unroll
        for (int i = 0; i < 2; ++i)
            #pragma unroll
            for (int j = 0; j < 2; ++j) acc[i][j] = zero4();

        #pragma unroll
        for (int ks = 0; ks < 8; ++ks) {
            const int kb = ks * 32 + quad * 8;
            short8 af[2];
            #pragma unroll
            for (int rt = 0; rt < 2; ++rt)
                af[rt] = *(const short8*)(&lds_x[(wrow + rt * 16 + m) * XS + kb]);
            #pragma unroll
            for (int rt = 0; rt < 2; ++rt)
                #pragma unroll
                for (int ct = 0; ct < 2; ++ct)
                    acc[rt][ct] = __builtin_amdgcn_mfma_f32_16x16x32_bf16(
                        af[rt], bfr[ct][ks], acc[rt][ct], 0, 0, 0);
        }

        #pragma unroll
        for (int ct = 0; ct < 2; ++ct) {
            const int col = ntile * 64 + wcol + ct * 16 + m;
            #pragma unroll
            for (int rt = 0; rt < 2; ++rt)
                #pragma unroll
                for (int r = 0; r < 4; ++r) {
                    const int bl = wrow + rt * 16 + quad * 4 + r;
                    xp[((size_t)t * B_ + bl) * H_ + col] =
                        f2bf(acc[rt][ct][r] + bias[ct]);
                }
        }
        __syncthreads();
    }
}

// ---------------------------------------------------------------------------
// Phase B: persistent recurrence, validated sc0 sc1 dataflow protocol,
// 8x8 geometry. Poll-storm-reduced: per-WG flags (8/group), wave0-only poll.
// Per-WG flag ordering: each wave drains its own publish stores (vmcnt 0),
// all waves pass S_a, THEN tid0 stores the WG flag -> flag implies the whole
// WG's h chunk is visible. Strictly stronger than the per-wave scheme.
// ---------------------------------------------------------------------------
#define LDS_STRIDE 1032   // row stride (shorts); rows 16B-aligned
#define PO_S 20           // per-wave out tile stride (shorts)
#define POLL_BOUND 4096

__global__ __launch_bounds__(512, 1) void rnn_kernel(
        const float* __restrict__ W_hh, const unsigned short* __restrict__ xp,
        unsigned short* __restrict__ hbuf, unsigned int* __restrict__ flags) {
    const int slice = blockIdx.x >> 3;   // 0..7 (128 H-cols each)
    const int group = blockIdx.x & 7;    // 0..7 (8 batch rows each)
    const int tid   = threadIdx.x;
    const int wave  = tid >> 6, lane = tid & 63;
    const int m     = lane & 15, quad = lane >> 4;
    const int col   = slice * SCOLS + wave * 16 + m;   // this lane's B column

    __shared__ unsigned short lds_h[GROWS * LDS_STRIDE];
    __shared__ unsigned short lds_po[8][GROWS * PO_S];

    // Preload W_hh B-frags: bfrag[ks] = W_hh[col][ks*32 + quad*8 ..]
    short8 bfrag[32];
    #pragma unroll
    for (int ks = 0; ks < 32; ++ks)
        bfrag[ks] = pack8(W_hh + (size_t)col * H_ + ks * 32 + quad * 8);

    unsigned int* gflags = flags + group * 8;       // 8 WG-flags per group
    unsigned int* myflag = gflags + slice;
    const unsigned int* pollp = gflags + (lane & 7);   // 8x redundant in-wave
    unsigned short* lds_po_w = &lds_po[wave][0];

    const int srow = tid >> 6, useg = tid & 63;       // staging role (8x64)
    const int prow = lane >> 3, pseg = lane & 7;      // publish role (8x8)

    for (int t = 0; t < T_; ++t) {
        const unsigned short* hsrc = hbuf + (size_t)(t & 1) * (B_ * H_)
                                          + (size_t)group * GROWS * H_;
        unsigned short* hdst = hbuf + (size_t)((t + 1) & 1) * (B_ * H_);

        // xp prefetch (plain cached loads). quads 2,3 duplicate 0,1 (unused).
        unsigned short xpv[4];
        {
            const unsigned short* xpp =
                xp + ((size_t)t * B_ + group * GROWS + (quad & 1) * 4) * H_ + col;
            #pragma unroll
            for (int r = 0; r < 4; ++r) xpv[r] = xpp[(size_t)r * H_];
        }

        // poll (WAVE 0 ONLY): all 8 WG-flags of this group >= t (bounded).
        // Waves 1-7 wait silently at the barrier -> no poll traffic at MALL.
        if (t > 0) {
            if (wave == 0) {
                const unsigned target = (unsigned)t;
                int spins = 0;
                while (true) {
                    unsigned fv;
                    asm volatile(
                        "global_load_dword %0, %1, off sc0 sc1\n\t"
                        "s_waitcnt vmcnt(0)"
                        : "=v"(fv) : "v"(pollp) : "memory");
                    if (__ballot(fv >= target) == ~0ull) break;
                    if (++spins >= POLL_BOUND) break;  // stall->absmax, no hang
                }
            }
            __syncthreads();   // B_poll: release stage once flags observed
        }

        // cooperative stage: 8 rows x 1024 bf16 (16 KB) -> LDS
        {
            const unsigned short* rp = hsrc + (size_t)srow * H_;
            uint4 sv0, sv1;
            asm volatile("global_load_dwordx4 %0, %1, off sc0 sc1"
                         : "=v"(sv0) : "v"(rp + useg * 8) : "memory");
            asm volatile("global_load_dwordx4 %0, %1, off sc0 sc1"
                         : "=v"(sv1) : "v"(rp + (useg + 64) * 8) : "memory");
            vdrain();
            *(uint4*)(&lds_h[srow * LDS_STRIDE + useg * 8]) = sv0;
            *(uint4*)(&lds_h[srow * LDS_STRIDE + (useg + 64) * 8]) = sv1;
        }
        __syncthreads();   // S_b: staged data visible to all waves

        // K loop: A rows 8..15 duplicate 0..7 via (m&7); C rows 8..15 unused.
        f32x4 acc[4];
        #pragma unroll
        for (int j = 0; j < 4; ++j) acc[j] = zero4();
        #pragma unroll
        for (int ks = 0; ks < 32; ks += 4) {
            #pragma unroll
            for (int j = 0; j < 4; ++j) {
                short8 a = *(const short8*)(
                    &lds_h[(m & 7) * LDS_STRIDE + (ks + j) * 32 + quad * 8]);
                acc[j] = __builtin_amdgcn_mfma_f32_16x16x32_bf16(
                    a, bfrag[ks + j], acc[j], 0, 0, 0);
            }
        }

        // epilogue: +xp, tanh -> per-wave LDS transpose tile (8 rows x 16 cols)
        if (quad < 2) {
            #pragma unroll
            for (int r = 0; r < 4; ++r) {
                float v = acc[0][r] + acc[1][r] + acc[2][r] + acc[3][r]
                        + bf2f(xpv[r]);
                v = tanhf(v);
                lds_po_w[(quad * 4 + r) * PO_S + m] = f2bf(v);
            }
        }
        // wave-local readback (compiler inserts lgkmcnt) + coherent publish
        {
            unsigned v = *(const unsigned*)(&lds_po_w[prow * PO_S + pseg * 2]);
            const void* p = hdst + (size_t)(group * GROWS + prow) * H_
                            + slice * SCOLS + wave * 16 + pseg * 2;
            asm volatile("global_store_dword %0, %1, off sc0 sc1"
                         :: "v"(p), "v"(v) : "memory");
            vdrain();   // own stores ack'd before S_a
        }
        __syncthreads();   // S_a: whole WG drained + done reading lds_h
        // per-WG flag: all 8 waves' chunks are visible at the coherence point
        if (tid == 0 && t < T_ - 1) {
            unsigned fv = (unsigned)(t + 1);
            asm volatile("global_store_dword %0, %1, off sc0 sc1"
                         :: "v"(myflag), "v"(fv) : "memory");
        }
    }
}

// ---------------------------------------------------------------------------
// Phase C: out[b][o] = h_final[b][:] . W_lin[o][:] + b_lin[o]; one wave/output
// ---------------------------------------------------------------------------
__global__ __launch_bounds__(256) void out_kernel(
        const unsigned short* __restrict__ hfinal, const float* __restrict__ W_lin,
        const float* __restrict__ b_lin, float* __restrict__ out) {
    const int gwave = (int)((blockIdx.x * 256 + threadIdx.x) >> 6);  // 0..8191
    const int lane  = threadIdx.x & 63;
    const int b = gwave >> 7, o = gwave & 127;

    const unsigned short* hp = hfinal + (size_t)b * H_ + lane * 16;
    const float*          wp = W_lin  + (size_t)o * H_ + lane * 16;
    float s = 0.f;
    #pragma unroll
    for (int j = 0; j < 16; ++j) s += bf2f(hp[j]) * wp[j];
    #pragma unroll
    for (int d = 32; d > 0; d >>= 1) s += __shfl_down(s, d, 64);
    if (lane == 0) out[(size_t)b * O_ + o] = s + b_lin[o];
}

// ---------------------------------------------------------------------------
extern "C" void kernel_launch(void* const* d_in, const int* in_sizes, int n_in,
                              void* d_out, int out_size, void* d_ws, size_t ws_size,
                              hipStream_t stream) {
    const float* x     = (const float*)d_in[0];
    const float* W_ih  = (const float*)d_in[1];
    const float* W_hh  = (const float*)d_in[2];
    const float* b_ih  = (const float*)d_in[3];
    const float* b_hh  = (const float*)d_in[4];
    const float* W_lin = (const float*)d_in[5];
    const float* b_lin = (const float*)d_in[6];

    const size_t XP_ELEMS = (size_t)T_ * B_ * H_;        // 33.5M bf16 = 64 MB
    unsigned short* xp    = (unsigned short*)d_ws;
    unsigned short* hbuf  = xp + XP_ELEMS;               // 2 x (64*1024) bf16
    unsigned int*   flags = (unsigned int*)(hbuf + 2 * (size_t)B_ * H_);

    // zero h ping-pong + flags
    (void)hipMemsetAsync(hbuf, 0,
                         2 * (size_t)B_ * H_ * sizeof(unsigned short)
                         + NGRP * 64 * sizeof(unsigned int), stream);

    dim3 gA(H_ / 64, T_ / 8);   // (ntile, tgroup)
    xproj_kernel<<<gA, 256, 0, stream>>>(x, W_ih, b_ih, b_hh, xp);
    rnn_kernel<<<64, 512, 0, stream>>>(W_hh, xp, hbuf, flags);
    out_kernel<<<(B_ * O_) / 4, 256, 0, stream>>>(hbuf, W_lin, b_lin, (float*)d_out);
}

// Round 12
// 1730.772 us; speedup vs baseline: 1.2565x; 1.0313x over previous
//
#include <hip/hip_runtime.h>
#include <cstdint>
#include <cstddef>

#define B_ 64
#define T_ 512
#define I_ 256
#define H_ 1024
#define O_ 128

// Phase-B geometry (validated r9-r11): 8 groups (8 batch rows) x 8 slices
// (128 H-cols), 512-thread WGs, sc0 sc1 exchange, per-WG flags, wave0 poll.
// THIS ROUND: Phase A FUSED into rnn_kernel (xp computed in-step from
// x + register-resident W_ih frags; xp array + xproj dispatch eliminated).
#define NGRP  8
#define NSLC  8
#define GROWS 8
#define SCOLS 128

typedef __attribute__((ext_vector_type(8))) short short8;   // 8 x bf16 frag
typedef __attribute__((ext_vector_type(4))) float f32x4;    // MFMA accumulator

__device__ __forceinline__ unsigned short f2bf(float f) {
    union { float f; unsigned int u; } v; v.f = f;
    unsigned int r = v.u + 0x7fffu + ((v.u >> 16) & 1u);   // RNE
    return (unsigned short)(r >> 16);
}
__device__ __forceinline__ float bf2f(unsigned short h) {
    union { float f; unsigned int u; } v; v.u = ((unsigned int)h) << 16;
    return v.f;
}
__device__ __forceinline__ short8 pack8(const float* p) {
    float4 a = *(const float4*)p;
    float4 b = *(const float4*)(p + 4);
    short8 r;
    r[0] = (short)f2bf(a.x); r[1] = (short)f2bf(a.y);
    r[2] = (short)f2bf(a.z); r[3] = (short)f2bf(a.w);
    r[4] = (short)f2bf(b.x); r[5] = (short)f2bf(b.y);
    r[6] = (short)f2bf(b.z); r[7] = (short)f2bf(b.w);
    return r;
}
__device__ __forceinline__ f32x4 zero4() {
    f32x4 v; v[0] = 0.f; v[1] = 0.f; v[2] = 0.f; v[3] = 0.f; return v;
}
__device__ __forceinline__ void vdrain() {
    asm volatile("s_waitcnt vmcnt(0)" ::: "memory");
}

// ---------------------------------------------------------------------------
// Phase B (+A fused): persistent recurrence, validated sc0 sc1 dataflow.
//   h_{t+1} = tanh( x[:,t,:]W_ih^T + b_ih + b_hh  +  h_t W_hh^T )
// Per WG: 8 batch rows x 128 H-cols. W_hh frags (32) + W_ih frags (8) in
// registers. x[t] staged to double-buffered LDS (plain cached loads, hidden
// under the coherent h-stage RT); acc_xp computed at top of step (buffer
// written last step; barrier-ordered). Exchange protocol byte-identical r11.
// ---------------------------------------------------------------------------
#define LDS_STRIDE 1032   // lds_h row stride (shorts); rows 16B-aligned
#define XSL 264           // lds_x row stride (shorts)
#define PO_S 20           // per-wave out tile stride (shorts)
#define POLL_BOUND 4096

__global__ __launch_bounds__(512, 1) void rnn_kernel(
        const float* __restrict__ W_hh, const float* __restrict__ W_ih,
        const float* __restrict__ b_ih, const float* __restrict__ b_hh,
        const float* __restrict__ x,
        unsigned short* __restrict__ hbuf, unsigned int* __restrict__ flags) {
    const int slice = blockIdx.x >> 3;   // 0..7 (128 H-cols each)
    const int group = blockIdx.x & 7;    // 0..7 (8 batch rows each)
    const int tid   = threadIdx.x;
    const int wave  = tid >> 6, lane = tid & 63;
    const int m     = lane & 15, quad = lane >> 4;
    const int col   = slice * SCOLS + wave * 16 + m;   // this lane's B column

    __shared__ unsigned short lds_h[GROWS * LDS_STRIDE];
    __shared__ unsigned short lds_po[8][GROWS * PO_S];
    __shared__ unsigned short lds_x2[2][GROWS * XSL];

    // Preload W_hh B-frags (as r11) + W_ih B-frags + fused bias
    short8 bfrag[32];
    #pragma unroll
    for (int ks = 0; ks < 32; ++ks)
        bfrag[ks] = pack8(W_hh + (size_t)col * H_ + ks * 32 + quad * 8);
    short8 bfragIH[8];
    #pragma unroll
    for (int ks = 0; ks < 8; ++ks)
        bfragIH[ks] = pack8(W_ih + (size_t)col * I_ + ks * 32 + quad * 8);
    const float biasc = b_ih[col] + b_hh[col];

    unsigned int* gflags = flags + group * 8;       // 8 WG-flags per group
    unsigned int* myflag = gflags + slice;
    const unsigned int* pollp = gflags + (lane & 7);
    unsigned short* lds_po_w = &lds_po[wave][0];

    const int srow = tid >> 6, useg = tid & 63;       // staging role (8x64)
    const int prow = lane >> 3, pseg = lane & 7;      // publish role (8x8)

    // prologue: stage x[t=0] rows into lds_x2[0]
    {
        float4 v = *(const float4*)(
            x + ((size_t)(group * GROWS + srow) * T_ + 0) * I_ + useg * 4);
        uint2 p;
        p.x = (unsigned)f2bf(v.x) | ((unsigned)f2bf(v.y) << 16);
        p.y = (unsigned)f2bf(v.z) | ((unsigned)f2bf(v.w) << 16);
        *(uint2*)(&lds_x2[0][srow * XSL + useg * 4]) = p;
    }
    __syncthreads();

    for (int t = 0; t < T_; ++t) {
        const unsigned short* hsrc = hbuf + (size_t)(t & 1) * (B_ * H_)
                                          + (size_t)group * GROWS * H_;
        unsigned short* hdst = hbuf + (size_t)((t + 1) & 1) * (B_ * H_);

        // xp compute (independent of h): reads lds_x2[t&1] staged last step
        // (barrier-ordered: write < S_b(t-1) ... S_a(t-1) < this read)
        f32x4 axp = zero4();
        #pragma unroll
        for (int ks = 0; ks < 8; ++ks) {
            short8 a = *(const short8*)(
                &lds_x2[t & 1][(m & 7) * XSL + ks * 32 + quad * 8]);
            axp = __builtin_amdgcn_mfma_f32_16x16x32_bf16(
                a, bfragIH[ks], axp, 0, 0, 0);
        }

        // poll (WAVE 0 ONLY): all 8 WG-flags of this group >= t (bounded)
        if (t > 0) {
            if (wave == 0) {
                const unsigned target = (unsigned)t;
                int spins = 0;
                while (true) {
                    unsigned fv;
                    asm volatile(
                        "global_load_dword %0, %1, off sc0 sc1\n\t"
                        "s_waitcnt vmcnt(0)"
                        : "=v"(fv) : "v"(pollp) : "memory");
                    if (__ballot(fv >= target) == ~0ull) break;
                    if (++spins >= POLL_BOUND) break;  // stall->absmax, no hang
                }
            }
            __syncthreads();   // B_poll: release stage once flags observed
        }

        // cooperative stage: h (coherent, 16 KB) + x[t+1] (plain, 8 KB f32)
        {
            const unsigned short* rp = hsrc + (size_t)srow * H_;
            uint4 sv0, sv1;
            asm volatile("global_load_dwordx4 %0, %1, off sc0 sc1"
                         : "=v"(sv0) : "v"(rp + useg * 8) : "memory");
            asm volatile("global_load_dwordx4 %0, %1, off sc0 sc1"
                         : "=v"(sv1) : "v"(rp + (useg + 64) * 8) : "memory");
            if (t + 1 < T_) {
                float4 v = *(const float4*)(
                    x + ((size_t)(group * GROWS + srow) * T_ + (t + 1)) * I_
                      + useg * 4);
                uint2 p;
                p.x = (unsigned)f2bf(v.x) | ((unsigned)f2bf(v.y) << 16);
                p.y = (unsigned)f2bf(v.z) | ((unsigned)f2bf(v.w) << 16);
                *(uint2*)(&lds_x2[(t + 1) & 1][srow * XSL + useg * 4]) = p;
            }
            vdrain();
            *(uint4*)(&lds_h[srow * LDS_STRIDE + useg * 8]) = sv0;
            *(uint4*)(&lds_h[srow * LDS_STRIDE + (useg + 64) * 8]) = sv1;
        }
        __syncthreads();   // S_b: staged data visible to all waves

        // main K loop: A rows 8..15 duplicate 0..7 via (m&7)
        f32x4 acc[4];
        #pragma unroll
        for (int j = 0; j < 4; ++j) acc[j] = zero4();
        #pragma unroll
        for (int ks = 0; ks < 32; ks += 4) {
            #pragma unroll
            for (int j = 0; j < 4; ++j) {
                short8 a = *(const short8*)(
                    &lds_h[(m & 7) * LDS_STRIDE + (ks + j) * 32 + quad * 8]);
                acc[j] = __builtin_amdgcn_mfma_f32_16x16x32_bf16(
                    a, bfrag[ks + j], acc[j], 0, 0, 0);
            }
        }

        // epilogue: + xp(f32) + bias, tanh -> per-wave LDS transpose tile
        if (quad < 2) {
            #pragma unroll
            for (int r = 0; r < 4; ++r) {
                float v = acc[0][r] + acc[1][r] + acc[2][r] + acc[3][r]
                        + axp[r] + biasc;
                v = tanhf(v);
                lds_po_w[(quad * 4 + r) * PO_S + m] = f2bf(v);
            }
        }
        // wave-local readback + coherent publish + own-store drain
        {
            unsigned v = *(const unsigned*)(&lds_po_w[prow * PO_S + pseg * 2]);
            const void* p = hdst + (size_t)(group * GROWS + prow) * H_
                            + slice * SCOLS + wave * 16 + pseg * 2;
            asm volatile("global_store_dword %0, %1, off sc0 sc1"
                         :: "v"(p), "v"(v) : "memory");
            vdrain();
        }
        __syncthreads();   // S_a: whole WG drained + done reading lds_h/lds_x
        // per-WG flag: whole WG's h chunk visible at the coherence point
        if (tid == 0 && t < T_ - 1) {
            unsigned fv = (unsigned)(t + 1);
            asm volatile("global_store_dword %0, %1, off sc0 sc1"
                         :: "v"(myflag), "v"(fv) : "memory");
        }
    }
}

// ---------------------------------------------------------------------------
// Phase C: out[b][o] = h_final[b][:] . W_lin[o][:] + b_lin[o]; one wave/output
// ---------------------------------------------------------------------------
__global__ __launch_bounds__(256) void out_kernel(
        const unsigned short* __restrict__ hfinal, const float* __restrict__ W_lin,
        const float* __restrict__ b_lin, float* __restrict__ out) {
    const int gwave = (int)((blockIdx.x * 256 + threadIdx.x) >> 6);  // 0..8191
    const int lane  = threadIdx.x & 63;
    const int b = gwave >> 7, o = gwave & 127;

    const unsigned short* hp = hfinal + (size_t)b * H_ + lane * 16;
    const float*          wp = W_lin  + (size_t)o * H_ + lane * 16;
    float s = 0.f;
    #pragma unroll
    for (int j = 0; j < 16; ++j) s += bf2f(hp[j]) * wp[j];
    #pragma unroll
    for (int d = 32; d > 0; d >>= 1) s += __shfl_down(s, d, 64);
    if (lane == 0) out[(size_t)b * O_ + o] = s + b_lin[o];
}

// ---------------------------------------------------------------------------
extern "C" void kernel_launch(void* const* d_in, const int* in_sizes, int n_in,
                              void* d_out, int out_size, void* d_ws, size_t ws_size,
                              hipStream_t stream) {
    const float* x     = (const float*)d_in[0];
    const float* W_ih  = (const float*)d_in[1];
    const float* W_hh  = (const float*)d_in[2];
    const float* b_ih  = (const float*)d_in[3];
    const float* b_hh  = (const float*)d_in[4];
    const float* W_lin = (const float*)d_in[5];
    const float* b_lin = (const float*)d_in[6];

    unsigned short* hbuf  = (unsigned short*)d_ws;       // 2 x (64*1024) bf16
    unsigned int*   flags = (unsigned int*)(hbuf + 2 * (size_t)B_ * H_);

    // zero h ping-pong + flags
    (void)hipMemsetAsync(hbuf, 0,
                         2 * (size_t)B_ * H_ * sizeof(unsigned short)
                         + NGRP * 64 * sizeof(unsigned int), stream);

    rnn_kernel<<<64, 512, 0, stream>>>(W_hh, W_ih, b_ih, b_hh, x, hbuf, flags);
    out_kernel<<<(B_ * O_) / 4, 256, 0, stream>>>(hbuf, W_lin, b_lin, (float*)d_out);
}